// Round 6
// baseline (436.725 us; speedup 1.0000x reference)
//
#include <hip/hip_runtime.h>

// Problem constants
#define K 256
#define D 128
#define HW 1024          // H*W
#define CHW 131072       // D*HW (per-batch stride of z)
#define N_TOT 131072     // B*H*W
#define NELEM 16777216   // N_TOT * D

// Workspace layout (float/dword indices)
#define WS_C2 0
#define WS_ENCSUM 256
#define WS_ENCB 512
#define WS_LOSS 33280
#define WS_FLAGCNT 33281
#define WS_LIST 33282
#define FLAG_CAP 16384
#define WS_PART 49666            // 64 partial copies of (K*D + K)
#define PBLK 64
#define PSTRIDE 33024            // K*D + K
#define WS_CBT (WS_PART + PBLK * PSTRIDE)   // 2163202, cbT[d][k] fp32
#define WS_CBH 2195972           // bf16-hi swizzled B frags, 16384 dwords (16B aligned)
#define WS_CBL 2212356           // bf16-lo swizzled B frags, 16384 dwords
// total ws: 2228740*4 B = 8.91 MB

// Output layout (float indices, outputs concatenated in return order)
#define OUT_Q 0
#define OUT_IDX 16777216
#define OUT_COMMIT 16908288
#define OUT_CBLOSS 16908289
#define OUT_NEWCB 16908290
#define OUT_NEWCNT 16941058
#define OUT_NEWW 16941314

#define TAU 3e-4f
#define MT 64            // n-tile per block in k_main
#define ZST 68           // zs row stride (64 + 4 pad; 17 float4)

typedef __attribute__((ext_vector_type(8))) short short8;
typedef __attribute__((ext_vector_type(4))) float floatx4;

// Split x into truncated-bf16 hi and bf16 lo (hi exact-subtracted remainder).
__device__ __forceinline__ void cvt_split(const float* xv, short8* hi, short8* lo) {
    union U { uint32_t u[4]; short8 s; } H, L;
    #pragma unroll
    for (int p = 0; p < 4; ++p) {
        uint32_t u0 = __float_as_uint(xv[2 * p]);
        uint32_t u1 = __float_as_uint(xv[2 * p + 1]);
        H.u[p] = (u0 >> 16) | (u1 & 0xFFFF0000u);
        float h0 = __uint_as_float(u0 & 0xFFFF0000u);
        float h1 = __uint_as_float(u1 & 0xFFFF0000u);
        float l0 = xv[2 * p] - h0;
        float l1 = xv[2 * p + 1] - h1;
        L.u[p] = (__float_as_uint(l0) >> 16) | (__float_as_uint(l1) & 0xFFFF0000u);
    }
    *hi = H.s; *lo = L.s;
}

// ---------------------------------------------------------------------------
// Kernel 1: blk<128: cbT transpose row d=blk. blk==128: c2 (numpy pairwise-8)
// + zero loss/flag. blk>128: bf16 hi/lo split of cb into MFMA-B fragment
// order: frag g=(ds*16+ktg), lane holds code=ktg*16+(lane&15),
// d = ds*32 + (lane>>4)*8 + j, 8 bf16 = one dwordx4.
// ---------------------------------------------------------------------------
__global__ void k_prep(const float* __restrict__ cb, float* __restrict__ ws) {
    #pragma clang fp contract(off)
    const int blk = blockIdx.x, t = threadIdx.x;
    if (blk < 128) {
        ws[WS_CBT + blk * K + t] = cb[(size_t)t * D + blk];
    } else if (blk == 128) {
        int k = t;
        if (k == 0) { ws[WS_LOSS] = 0.0f; ((int*)ws)[WS_FLAGCNT] = 0; }
        const float* row = cb + (size_t)k * D;
        float r[8];
        #pragma unroll
        for (int j = 0; j < 8; ++j) r[j] = row[j] * row[j];
        for (int i = 8; i < D; i += 8) {
            #pragma unroll
            for (int j = 0; j < 8; ++j) r[j] = r[j] + row[i + j] * row[i + j];
        }
        ws[WS_C2 + k] = ((r[0] + r[1]) + (r[2] + r[3])) + ((r[4] + r[5]) + (r[6] + r[7]));
    } else {
        int e = (blk - 129) * 4 + (t >> 6);   // frag id 0..63
        int lane = t & 63;
        int ds = e >> 4, ktg = e & 15;
        int code = ktg * 16 + (lane & 15);
        int d0 = ds * 32 + (lane >> 4) * 8;
        float xv[8];
        #pragma unroll
        for (int j = 0; j < 8; ++j) xv[j] = cb[(size_t)code * D + d0 + j];
        short8 h, l;
        cvt_split(xv, &h, &l);
        union V { short8 s; uint4 u; } Hv, Lv;
        Hv.s = h; Lv.s = l;
        uint32_t* wsu = (uint32_t*)ws;
        reinterpret_cast<uint4*>(wsu + WS_CBH)[e * 64 + lane] = Hv.u;
        reinterpret_cast<uint4*>(wsu + WS_CBL)[e * 64 + lane] = Lv.u;
    }
}

// ---------------------------------------------------------------------------
// Kernel 2: MFMA GEMM-argmax. Block = 64 n (4 waves x 16-n m-tile).
// B chunk (64 codes, hi+lo frags) staged into LDS once per block per chunk;
// waves consume via ds_read_b128. A frags (32 VGPR) built once from zs.
// Score S = z.c - 0.5*c2 via bf16 split: zh*ch + zh*cl + zl*ch.
// Near-ties (gap < TAU) -> exact fallback.
// ---------------------------------------------------------------------------
__global__ void __launch_bounds__(256, 2)
k_main(const float* __restrict__ z, float* __restrict__ ws,
       float* __restrict__ out) {
    __shared__ float zs[D * ZST];      // zs[d][n], 34.8 KB
    __shared__ float bs[8192];         // B chunk frags (32 x 64 lanes x 16B), 32 KB
    __shared__ int bkA[MT];

    const int t = threadIdx.x;
    const int blk = blockIdx.x;
    const int n0 = blk * MT;
    const int b = n0 >> 10;
    const int hw0 = n0 & 1023;

    // --- stage z tile: zs[d][n] via float4 over hw ---
    {
        const float4* __restrict__ z4 = reinterpret_cast<const float4*>(z);
        float4* __restrict__ zs4w = reinterpret_cast<float4*>(zs);
        const size_t zbase4 = (size_t)b * (CHW / 4) + (hw0 >> 2);
        #pragma unroll
        for (int i = 0; i < 8; ++i) {
            int f = i * 256 + t;
            int dd = f >> 4, n4 = f & 15;
            zs4w[dd * (ZST / 4) + n4] = z4[zbase4 + (size_t)dd * (HW / 4) + n4];
        }
    }
    __syncthreads();

    const int lane = t & 63, w = t >> 6;
    const int col = lane & 15, quad = lane >> 4;
    const int m = w * 16;

    // --- A fragments: convert once, hold in 32 VGPRs (4 dsteps, hi+lo) ---
    short8 Ah[4], Al[4];
    #pragma unroll
    for (int ds = 0; ds < 4; ++ds) {
        float xv[8];
        #pragma unroll
        for (int j = 0; j < 8; ++j)
            xv[j] = zs[(ds * 32 + quad * 8 + j) * ZST + m + col];
        cvt_split(xv, &Ah[ds], &Al[ds]);
    }

    // --- preload c2 (per-lane col) for all chunks ---
    const float* __restrict__ c2s = ws + WS_C2;
    float c2v[4][4];
    #pragma unroll
    for (int ch = 0; ch < 4; ++ch)
        #pragma unroll
        for (int kt = 0; kt < 4; ++kt)
            c2v[ch][kt] = c2s[ch * 64 + kt * 16 + col];

    const uint32_t* wsu = (const uint32_t*)ws;
    const uint4* __restrict__ bg4h = reinterpret_cast<const uint4*>(wsu + WS_CBH);
    const uint4* __restrict__ bg4l = reinterpret_cast<const uint4*>(wsu + WS_CBL);
    uint4* __restrict__ bs4 = reinterpret_cast<uint4*>(bs);

    float best[4], second[4];
    int bk[4];
    #pragma unroll
    for (int r = 0; r < 4; ++r) { best[r] = -3.4e38f; second[r] = -3.4e38f; bk[r] = 0; }

    for (int ch = 0; ch < 4; ++ch) {
        __syncthreads();   // prev-chunk bs reads done
        // stage B chunk: LDS frag f (0..15 hi, 16..31 lo); wave w stages f = i*4+w
        #pragma unroll
        for (int i = 0; i < 8; ++i) {
            int f = i * 4 + w;                   // wave-uniform
            uint4 v;
            if (f < 16) {
                int g = (f >> 2) * 16 + ch * 4 + (f & 3);
                v = bg4h[g * 64 + lane];
            } else {
                int f2 = f - 16;
                int g = (f2 >> 2) * 16 + ch * 4 + (f2 & 3);
                v = bg4l[g * 64 + lane];
            }
            bs4[f * 64 + lane] = v;
        }
        __syncthreads();

        floatx4 acc[4];
        #pragma unroll
        for (int kt = 0; kt < 4; ++kt) {
            float iv = -0.5f * c2v[ch][kt];
            acc[kt][0] = iv; acc[kt][1] = iv; acc[kt][2] = iv; acc[kt][3] = iv;
        }
        #pragma unroll
        for (int ds = 0; ds < 4; ++ds) {
            short8 Bh[4], Bl[4];
            #pragma unroll
            for (int kt = 0; kt < 4; ++kt) {
                union V { uint4 u; short8 s; } X, Y;
                X.u = bs4[(ds * 4 + kt) * 64 + lane];
                Y.u = bs4[(16 + ds * 4 + kt) * 64 + lane];
                Bh[kt] = X.s; Bl[kt] = Y.s;
            }
            #pragma unroll
            for (int kt = 0; kt < 4; ++kt) {
                acc[kt] = __builtin_amdgcn_mfma_f32_16x16x32_bf16(Ah[ds], Bh[kt], acc[kt], 0, 0, 0);
                acc[kt] = __builtin_amdgcn_mfma_f32_16x16x32_bf16(Ah[ds], Bl[kt], acc[kt], 0, 0, 0);
                acc[kt] = __builtin_amdgcn_mfma_f32_16x16x32_bf16(Al[ds], Bh[kt], acc[kt], 0, 0, 0);
            }
        }
        // fold chunk into per-lane top-2 (k increasing)
        #pragma unroll
        for (int kt = 0; kt < 4; ++kt) {
            int kc = ch * 64 + kt * 16 + col;
            #pragma unroll
            for (int r = 0; r < 4; ++r) {
                float s = acc[kt][r];
                if (s > best[r]) { second[r] = best[r]; best[r] = s; bk[r] = kc; }
                else if (s > second[r]) second[r] = s;
            }
        }
    }

    // --- merge top-2 across the 16 cols ---
    #pragma unroll
    for (int off = 1; off < 16; off <<= 1) {
        #pragma unroll
        for (int r = 0; r < 4; ++r) {
            float ob = __shfl_xor(best[r], off);
            float os = __shfl_xor(second[r], off);
            int ok = __shfl_xor(bk[r], off);
            float nb = fmaxf(best[r], ob);
            float ns = fmaxf(fminf(best[r], ob), fmaxf(second[r], os));
            bk[r] = (ob > best[r]) ? ok : bk[r];
            best[r] = nb; second[r] = ns;
        }
    }

    if (col == 0) {
        #pragma unroll
        for (int r = 0; r < 4; ++r) {
            int nl = m + quad * 4 + r;
            int n = n0 + nl;
            int KB = bk[r];
            bool fl = (best[r] - second[r]) < TAU;
            if (fl) {
                int slot = atomicAdd((int*)ws + WS_FLAGCNT, 1);
                if (slot < FLAG_CAP) ((int*)ws)[WS_LIST + slot] = n;
                else fl = false;
            }
            if (!fl) { out[OUT_IDX + n] = (float)KB; bkA[nl] = KB; }
            else bkA[nl] = -1;
        }
    }
    __syncthreads();

    // --- epilogue: q write (coalesced over n) + loss partial ---
    const int nl = t & 63, dp = t >> 6;
    const int bkn = bkA[nl];
    float lsum = 0.0f;
    if (bkn >= 0) {
        const float* __restrict__ ct = ws + WS_CBT;
        float* __restrict__ op = out + OUT_Q + (size_t)b * CHW + hw0 + nl;
        #pragma unroll 4
        for (int i = 0; i < 32; ++i) {
            int d = dp * 32 + i;
            float zv = zs[d * ZST + nl];
            float q = ct[d * K + bkn];            // cbT[d][k] gather, L2-hot
            op[(size_t)d * HW] = zv + (q - zv);   // straight-through rounding
            float tdf = zv - q;
            lsum = fmaf(tdf, tdf, lsum);
        }
    }
    #pragma unroll
    for (int off = 32; off >= 1; off >>= 1) lsum += __shfl_down(lsum, off);
    if ((t & 63) == 0) atomicAdd(ws + WS_LOSS, lsum);
}

// ---------------------------------------------------------------------------
// Kernel 3: exact fallback for flagged n's (numpy-bitwise distance pipeline).
// ---------------------------------------------------------------------------
__global__ void k_fallback(const float* __restrict__ z, const float* __restrict__ cb,
                           float* __restrict__ ws, float* __restrict__ out) {
    #pragma clang fp contract(off)
    const int tid = threadIdx.x;
    __shared__ float zsF[D];
    __shared__ float z2s;
    __shared__ float dvals[K];
    __shared__ int kidx[K];

    int cnt = ((const int*)ws)[WS_FLAGCNT];
    if (cnt > FLAG_CAP) cnt = FLAG_CAP;

    for (int li = blockIdx.x; li < cnt; li += gridDim.x) {
        const int n = ((const int*)ws)[WS_LIST + li];
        const int b = n >> 10;
        const int hw = n & 1023;

        if (tid < D) zsF[tid] = z[(size_t)b * CHW + (size_t)tid * HW + hw];
        __syncthreads();

        if (tid == 0) {
            float r[8];
            #pragma unroll
            for (int j = 0; j < 8; ++j) r[j] = zsF[j] * zsF[j];
            for (int i = 8; i < D; i += 8) {
                #pragma unroll
                for (int j = 0; j < 8; ++j) r[j] = r[j] + zsF[i + j] * zsF[i + j];
            }
            z2s = ((r[0] + r[1]) + (r[2] + r[3])) + ((r[4] + r[5]) + (r[6] + r[7]));
        }
        __syncthreads();

        {
            const float* row = cb + (size_t)tid * D;
            double acc = 0.0;
            for (int d = 0; d < D; ++d) acc += (double)zsF[d] * (double)row[d];
            float zc = (float)acc;
            float dq = (z2s - 2.0f * zc) + ws[WS_C2 + tid];
            dvals[tid] = dq;
            kidx[tid] = tid;
        }
        __syncthreads();

        for (int s = K / 2; s > 0; s >>= 1) {
            if (tid < s) {
                float ov = dvals[tid + s]; int ok = kidx[tid + s];
                float mv = dvals[tid];     int mk2 = kidx[tid];
                if (ov < mv || (ov == mv && ok < mk2)) { dvals[tid] = ov; kidx[tid] = ok; }
            }
            __syncthreads();
        }
        const int bk = kidx[0];
        __syncthreads();

        float t2 = 0.0f;
        if (tid == 0) out[OUT_IDX + n] = (float)bk;
        if (tid < D) {
            float q = cb[(size_t)bk * D + tid];
            out[OUT_Q + (size_t)b * CHW + (size_t)tid * HW + hw] = zsF[tid] + (q - zsF[tid]);
            float t = zsF[tid] - q;
            t2 = t * t;
        }
        dvals[tid] = t2;
        __syncthreads();
        for (int s = K / 2; s > 0; s >>= 1) {
            if (tid < s) dvals[tid] += dvals[tid + s];
            __syncthreads();
        }
        if (tid == 0) atomicAdd(ws + WS_LOSS, dvals[0]);
        __syncthreads();
    }
}

// ---------------------------------------------------------------------------
// Kernel 4: EMA gather, sort-based, NO accumulation atomics.
// 512 blocks x 1024 threads; block = (batch-pair p = blk>>3, d-chunk c = blk&7).
// Counting-sort n by k in LDS (redundant per chunk, cheap), then lane (k,d)
// walks its bucket with plain ds_read + register accumulate.
// ---------------------------------------------------------------------------
#define GN 2048
#define ZSTR 2052        // 512 float4 + 4
__global__ void __launch_bounds__(1024, 1)
k_emagather(const float* __restrict__ z, const float* __restrict__ out,
            float* __restrict__ ws) {
    __shared__ float zsg[16 * ZSTR];   // 16-d chunk x 2048 n, 131.3 KB
    __shared__ int idxs[GN];
    __shared__ int order[GN];
    __shared__ int cnt[K];
    __shared__ int incl[K];
    __shared__ int startk[K];
    __shared__ int fill[K];

    const int t = threadIdx.x;
    const int p = blockIdx.x >> 3;     // batch pair
    const int c = blockIdx.x & 7;      // d-chunk (16 d)

    for (int j = t; j < GN; j += 1024)
        idxs[j] = (int)out[OUT_IDX + (size_t)p * GN + j];
    if (t < K) cnt[t] = 0;
    __syncthreads();
    for (int j = t; j < GN; j += 1024) atomicAdd(&cnt[idxs[j]], 1);
    __syncthreads();
    if (t < K) incl[t] = cnt[t];
    __syncthreads();
    for (int off = 1; off < K; off <<= 1) {
        int v = 0;
        if (t < K) { v = incl[t]; if (t >= off) v += incl[t - off]; }
        __syncthreads();
        if (t < K) incl[t] = v;
        __syncthreads();
    }
    if (t < K) { startk[t] = incl[t] - cnt[t]; fill[t] = incl[t] - cnt[t]; }
    __syncthreads();
    for (int j = t; j < GN; j += 1024) {
        int k = idxs[j];
        int pos = atomicAdd(&fill[k], 1);
        order[pos] = j;
    }

    float* __restrict__ pout = ws + WS_PART + (size_t)p * PSTRIDE;
    if (c == 0 && t < K) pout[K * D + t] = (float)cnt[t];

    // stage zsg[d2][n] for d = c*16 + d2
    const float4* __restrict__ z4 = reinterpret_cast<const float4*>(z);
    for (int j = t; j < 16 * 512; j += 1024) {
        int d2 = j >> 9, n4 = j & 511;
        int bb = n4 >> 8, hw4 = n4 & 255;
        float4 v = z4[(size_t)(2 * p + bb) * (CHW / 4)
                      + (size_t)(c * 16 + d2) * (HW / 4) + hw4];
        *reinterpret_cast<float4*>(&zsg[d2 * ZSTR + 4 * n4]) = v;
    }
    __syncthreads();

    const int dl = t & 15;
    const int k0 = (t >> 4) * 4;       // 4 k's per thread
    const float* __restrict__ zrow = zsg + dl * ZSTR;
    #pragma unroll
    for (int kk = 0; kk < 4; ++kk) {
        int k = k0 + kk;
        int s = startk[k], e = s + cnt[k];
        float a = 0.0f;
        for (int q = s; q < e; ++q) a += zrow[order[q]];
        pout[(size_t)k * D + c * 16 + dl] = a;
    }
}

// ---------------------------------------------------------------------------
// Kernel 5: reduce 64 partial copies -> encbatch / encsum in ws
// ---------------------------------------------------------------------------
__global__ void k_emareduce(float* __restrict__ ws) {
    int e = blockIdx.x * 256 + threadIdx.x;
    if (e >= PSTRIDE) return;
    const float* __restrict__ p = ws + WS_PART + e;
    float s = 0.0f;
    #pragma unroll 8
    for (int g = 0; g < PBLK; ++g) s += p[(size_t)g * PSTRIDE];
    if (e < K * D) ws[WS_ENCB + e] = s;
    else ws[WS_ENCSUM + (e - K * D)] = s;
}

// ---------------------------------------------------------------------------
// Kernel 6: finalize EMA outputs + losses. One block of 256 threads.
// ---------------------------------------------------------------------------
__global__ void k_finalize(const float* __restrict__ ema_count,
                           const float* __restrict__ ema_weight,
                           const float* __restrict__ ws, float* __restrict__ out) {
    #pragma clang fp contract(off)
    const int tid = threadIdx.x;
    __shared__ float red[K];
    __shared__ float normc[K];

    const float DEC = 0.99f;
    const float OMD = (float)(1.0 - 0.99);

    float nc = DEC * ema_count[tid] + OMD * ws[WS_ENCSUM + tid];
    out[OUT_NEWCNT + tid] = nc;
    red[tid] = nc;
    __syncthreads();
    for (int s = K / 2; s > 0; s >>= 1) {
        if (tid < s) red[tid] += red[tid + s];
        __syncthreads();
    }
    const float nt = red[0];
    normc[tid] = (nc + 1e-5f) / (nt + 0.00256f) * nt;
    __syncthreads();

    for (int i = tid; i < K * D; i += 256) {
        int k = i >> 7;
        float nw = DEC * ema_weight[i] + OMD * ws[WS_ENCB + i];
        out[OUT_NEWW + i] = nw;
        out[OUT_NEWCB + i] = nw / normc[k];
    }
    if (tid == 0) {
        float m = ws[WS_LOSS] / 16777216.0f;
        out[OUT_CBLOSS] = m;
        out[OUT_COMMIT] = 0.25f * m;
    }
}

// ---------------------------------------------------------------------------
extern "C" void kernel_launch(void* const* d_in, const int* in_sizes, int n_in,
                              void* d_out, int out_size, void* d_ws, size_t ws_size,
                              hipStream_t stream) {
    const float* z = (const float*)d_in[0];
    const float* cb = (const float*)d_in[1];
    const float* ema_count = (const float*)d_in[2];
    const float* ema_weight = (const float*)d_in[3];
    float* out = (float*)d_out;
    float* ws = (float*)d_ws;

    k_prep<<<145, 256, 0, stream>>>(cb, ws);
    k_main<<<N_TOT / MT, 256, 0, stream>>>(z, ws, out);
    k_fallback<<<1024, 256, 0, stream>>>(z, cb, ws, out);
    k_emagather<<<512, 1024, 0, stream>>>(z, out, ws);
    k_emareduce<<<129, 256, 0, stream>>>(ws);
    k_finalize<<<1, 256, 0, stream>>>(ema_count, ema_weight, ws, out);
}